// Round 2
// baseline (880.700 us; speedup 1.0000x reference)
//
#include <hip/hip_runtime.h>
#include <hip/hip_bf16.h>
#include <cmath>

// DXVAE: 7-node sequential graph GRU + VAE head, B=2048, H=1024.
// I/O dtype: float32 (per reference); internal GEMMs: bf16 MFMA 16x16x32,
// fp32 accumulation. Weights pre-converted to bf16 in workspace once/launch.
// Key algebraic optimization: per-neighbor projections h@Wg1^T, h@Wg2^T,
// h@Wm1^T, h@Wm2^T are stage-invariant -> precompute once per node (P array),
// stage combine is a cheap masked elementwise reduce.

typedef __hip_bfloat16 bf16;
typedef __attribute__((ext_vector_type(8))) short bf16x8;   // 8 bf16 = 4 VGPRs (A/B frag)
typedef __attribute__((ext_vector_type(4))) float f32x4;    // C/D frag

constexpr int BATCH = 2048;
constexpr int HD    = 1024;
constexpr size_t BH = (size_t)BATCH * HD;

__device__ __forceinline__ float bf2f(bf16 v){ return __bfloat162float(v); }
__device__ __forceinline__ bf16  f2bf(float v){ return __float2bfloat16(v); }
__device__ __forceinline__ float sigm(float x){ return 1.0f/(1.0f+__expf(-x)); }

// ---------------------------------------------------------------------------
// f32 -> bf16 conversion, 4 elems/thread (all sizes are multiples of 4)
// ---------------------------------------------------------------------------
__global__ void cvt4(const float* __restrict__ in, bf16* __restrict__ out, int n4){
  int i = blockIdx.x*256 + threadIdx.x;
  if (i >= n4) return;
  float4 v = reinterpret_cast<const float4*>(in)[i];
  bf16 o[4] = {f2bf(v.x), f2bf(v.y), f2bf(v.z), f2bf(v.w)};
  *reinterpret_cast<ushort4*>(out + 4*(size_t)i) = *reinterpret_cast<const ushort4*>(o);
}

// Wgm (4096x1024) = [Wg[:,:1024]; Wg[:,1024:]; Wm[:,:1024]; Wm[:,1024:]], bf16
__global__ void pack_wgm(const float* __restrict__ Wg, const float* __restrict__ Wm,
                         bf16* __restrict__ outW){
  int i = blockIdx.x*256 + threadIdx.x;          // < 4096*256
  int c = i >> 8;                                // 0..4095
  int f0 = (i & 255)*4;
  int j = c >> 10, h = c & 1023;
  const float* src = (j < 2) ? Wg : Wm;
  float4 v = *reinterpret_cast<const float4*>(src + (size_t)h*2048 + ((j & 1) ? 1024 : 0) + f0);
  bf16 o[4] = {f2bf(v.x), f2bf(v.y), f2bf(v.z), f2bf(v.w)};
  *reinterpret_cast<ushort4*>(outW + (size_t)c*1024 + f0) = *reinterpret_cast<const ushort4*>(o);
}

// Wms (512x1024) = [Wmu; Wstd], bf16
__global__ void pack_wms(const float* __restrict__ Wmu, const float* __restrict__ Wstd,
                         bf16* __restrict__ outW){
  int i = blockIdx.x*256 + threadIdx.x;          // < 512*256
  int c = i >> 8;
  int f0 = (i & 255)*4;
  const float* src = (c < 256) ? (Wmu + (size_t)c*1024) : (Wstd + (size_t)(c-256)*1024);
  float4 v = *reinterpret_cast<const float4*>(src + f0);
  bf16 o[4] = {f2bf(v.x), f2bf(v.y), f2bf(v.z), f2bf(v.w)};
  *reinterpret_cast<ushort4*>(outW + (size_t)c*1024 + f0) = *reinterpret_cast<const ushort4*>(o);
}

// ---------------------------------------------------------------------------
// Stage combine: H_in[b,h] = sum_{k>v} sigmoid(p*Pg1+s*Pg2+bg) * (p*Pm1+s*Pm2)
// P layout: P[(k-1)*4 + j][b][h], j = {Wg1,Wg2,Wm1,Wm2} projection of hidden[k]
// ---------------------------------------------------------------------------
__global__ __launch_bounds__(256) void combine_k(
    const bf16* __restrict__ P, const int* __restrict__ adj,
    const float* __restrict__ bg, bf16* __restrict__ Hin, int v)
{
  int b  = blockIdx.x;
  int h0 = threadIdx.x * 4;
  float bgv[4], acc[4] = {0.f,0.f,0.f,0.f};
  #pragma unroll
  for (int u=0;u<4;++u) bgv[u] = bg[h0+u];
  for (int k=v+1;k<7;++k){
    bool p = adj[b*49 + k*7 + v] > 0;
    bool s = adj[b*49 + v*7 + k] > 0;
    if (!p && !s) continue;                       // m == 0 -> zero contribution
    const bf16* base = P + (size_t)(k-1)*4*BH + (size_t)b*HD + h0;
    #pragma unroll
    for (int u=0;u<4;++u){
      float g1 = p ? bf2f(base[u])        : 0.f;
      float g2 = s ? bf2f(base[BH+u])     : 0.f;
      float m1 = p ? bf2f(base[2*BH+u])   : 0.f;
      float m2 = s ? bf2f(base[3*BH+u])   : 0.f;
      acc[u] += sigm(g1+g2+bgv[u]) * (m1+m2);
    }
  }
  #pragma unroll
  for (int u=0;u<4;++u) Hin[(size_t)b*HD + h0 + u] = f2bf(acc[u]);
}

// ---------------------------------------------------------------------------
// Fused GRU: out = GRU(x, h). Block tile: 64 batch rows x 64 H cols, 4 waves
// (2x2), each wave 32x32 per gate. Three gate accumulators share one A tile.
// gi = x@Wih^T done with one zero-padded K=32 MFMA step (xw=27 or 23).
// All matrix operands bf16 (pre-converted); biases f32.
// ---------------------------------------------------------------------------
__global__ __launch_bounds__(256) void gru_fused(
    const bf16* __restrict__ Ah,      // h input (B,1024) bf16: GEMM A and GRU h
    const bf16* __restrict__ Whh,     // (3072,1024) bf16
    const float* __restrict__ bhh,    // (3072)
    const bf16* __restrict__ Wih,     // (3072,xw) bf16
    const float* __restrict__ bih,    // (3072)
    const bf16* __restrict__ X,       // (B,7,27) bf16
    const int*  __restrict__ adj,     // (B,7,7)
    int v, int xw, int self_mask, int h_zero,
    bf16* __restrict__ out)           // (B,1024) bf16
{
  __shared__ __align__(16) bf16 As[64*40];       // +8 bf16 pad: b128 reads 2-way-free
  __shared__ __align__(16) bf16 Bs[3*64*40];
  const int tid  = threadIdx.x;
  const int rb0  = blockIdx.x*64, n0 = blockIdx.y*64;
  const int lane = tid & 63, wid = tid >> 6;
  const int wm   = wid >> 1, wn = wid & 1;
  const int quad = lane >> 4, l15 = lane & 15;
  const int ar   = tid >> 2, ak = (tid & 3)*8;   // staging: row 0..63, k-offset 0/8/16/24

  // ---- gi = x @ Wih^T (single K=32 step; x zero-padded, self-loop mask at staging)
  {
    int brow = rb0 + ar;
    bool xon = true;
    if (self_mask) xon = adj[brow*49 + v*7 + v] > 0;   // X_loop = self ? Xv : 0
    #pragma unroll
    for (int j=0;j<8;++j){
      int f = ak + j;
      As[ar*40 + ak + j] = (xon && f < xw) ? X[((size_t)brow*7 + v)*27 + f] : f2bf(0.f);
      #pragma unroll
      for (int g=0; g<3; ++g)
        Bs[(g*64 + ar)*40 + ak + j] =
            (f < xw) ? Wih[(size_t)(g*HD + n0 + ar)*xw + f] : f2bf(0.f);
    }
  }
  __syncthreads();
  f32x4 gi[3][2][2] = {};
  {
    bf16x8 afr[2], bfr[3][2];
    #pragma unroll
    for (int t=0;t<2;++t)
      afr[t] = *reinterpret_cast<const bf16x8*>(&As[(wm*32 + t*16 + l15)*40 + quad*8]);
    #pragma unroll
    for (int g=0;g<3;++g)
      #pragma unroll
      for (int t=0;t<2;++t)
        bfr[g][t] = *reinterpret_cast<const bf16x8*>(&Bs[(g*64 + wn*32 + t*16 + l15)*40 + quad*8]);
    #pragma unroll
    for (int g=0;g<3;++g)
      #pragma unroll
      for (int tm=0;tm<2;++tm)
        #pragma unroll
        for (int tn=0;tn<2;++tn)
          gi[g][tm][tn] = __builtin_amdgcn_mfma_f32_16x16x32_bf16(afr[tm], bfr[g][tn], gi[g][tm][tn], 0,0,0);
  }

  // ---- gh = h @ Whh^T (3 gates), K=1024 in BK=32 steps
  f32x4 acc[3][2][2] = {};
  if (!h_zero){
    for (int k0=0;k0<HD;k0+=32){
      uint4 av  = *reinterpret_cast<const uint4*>(Ah  + (size_t)(rb0+ar)*HD + k0 + ak);
      uint4 bv0 = *reinterpret_cast<const uint4*>(Whh + (size_t)(       n0+ar)*HD + k0 + ak);
      uint4 bv1 = *reinterpret_cast<const uint4*>(Whh + (size_t)(HD   + n0+ar)*HD + k0 + ak);
      uint4 bv2 = *reinterpret_cast<const uint4*>(Whh + (size_t)(2*HD + n0+ar)*HD + k0 + ak);
      __syncthreads();
      *reinterpret_cast<uint4*>(&As[ar*40 + ak])          = av;
      *reinterpret_cast<uint4*>(&Bs[(0*64+ar)*40 + ak])   = bv0;
      *reinterpret_cast<uint4*>(&Bs[(1*64+ar)*40 + ak])   = bv1;
      *reinterpret_cast<uint4*>(&Bs[(2*64+ar)*40 + ak])   = bv2;
      __syncthreads();
      bf16x8 afr[2], bfr[3][2];
      #pragma unroll
      for (int t=0;t<2;++t)
        afr[t] = *reinterpret_cast<const bf16x8*>(&As[(wm*32 + t*16 + l15)*40 + quad*8]);
      #pragma unroll
      for (int g=0;g<3;++g)
        #pragma unroll
        for (int t=0;t<2;++t)
          bfr[g][t] = *reinterpret_cast<const bf16x8*>(&Bs[(g*64 + wn*32 + t*16 + l15)*40 + quad*8]);
      #pragma unroll
      for (int g=0;g<3;++g)
        #pragma unroll
        for (int tm=0;tm<2;++tm)
          #pragma unroll
          for (int tn=0;tn<2;++tn)
            acc[g][tm][tn] = __builtin_amdgcn_mfma_f32_16x16x32_bf16(afr[tm], bfr[g][tn], acc[g][tm][tn], 0,0,0);
    }
  }

  // ---- GRU elementwise epilogue. C/D layout: col=lane&15, row=quad*4+reg.
  #pragma unroll
  for (int tn=0; tn<2; ++tn){
    int c = n0 + wn*32 + tn*16 + l15;
    float bir = bih[c], biz = bih[HD+c], bin_ = bih[2*HD+c];
    float bhr = bhh[c], bhz = bhh[HD+c], bhn  = bhh[2*HD+c];
    #pragma unroll
    for (int tm=0; tm<2; ++tm){
      #pragma unroll
      for (int i=0;i<4;++i){
        int b = rb0 + wm*32 + tm*16 + quad*4 + i;
        float r = sigm(gi[0][tm][tn][i] + bir + acc[0][tm][tn][i] + bhr);
        float z = sigm(gi[1][tm][tn][i] + biz + acc[1][tm][tn][i] + bhz);
        float n = tanhf(gi[2][tm][tn][i] + bin_ + r*(acc[2][tm][tn][i] + bhn));
        float h = h_zero ? 0.f : bf2f(Ah[(size_t)b*HD + c]);
        out[(size_t)b*HD + c] = f2bf((1.f - z)*n + z*h);
      }
    }
  }
}

// ---------------------------------------------------------------------------
// Generic GEMM C = A(2048x1024) @ W^T(Nx1024), bf16 in.
// FINAL=false: P-projection, out[((c>>10)*B + b)*1024 + (c&1023)], bf16.
// FINAL=true : mu/std head, bias + softplus on second half, f32 out = d_out.
// ---------------------------------------------------------------------------
template<bool FINAL>
__global__ __launch_bounds__(256) void gemm_bt(
    const bf16* __restrict__ A, const bf16* __restrict__ W,
    bf16* __restrict__ out, float* __restrict__ outF,
    const float* __restrict__ bmu, const float* __restrict__ bstd)
{
  __shared__ __align__(16) bf16 As[64*40];
  __shared__ __align__(16) bf16 Bs[64*40];
  const int tid  = threadIdx.x;
  const int rb0  = blockIdx.x*64, n0 = blockIdx.y*64;
  const int lane = tid & 63, wid = tid >> 6;
  const int wm   = wid >> 1, wn = wid & 1;
  const int quad = lane >> 4, l15 = lane & 15;
  const int ar   = tid >> 2, ak = (tid & 3)*8;

  f32x4 acc[2][2] = {};
  for (int k0=0;k0<HD;k0+=32){
    uint4 av = *reinterpret_cast<const uint4*>(A + (size_t)(rb0+ar)*HD + k0 + ak);
    uint4 bv = *reinterpret_cast<const uint4*>(W + (size_t)(n0 +ar)*HD + k0 + ak);
    __syncthreads();
    *reinterpret_cast<uint4*>(&As[ar*40 + ak]) = av;
    *reinterpret_cast<uint4*>(&Bs[ar*40 + ak]) = bv;
    __syncthreads();
    bf16x8 afr[2], bfr[2];
    #pragma unroll
    for (int t=0;t<2;++t){
      afr[t] = *reinterpret_cast<const bf16x8*>(&As[(wm*32 + t*16 + l15)*40 + quad*8]);
      bfr[t] = *reinterpret_cast<const bf16x8*>(&Bs[(wn*32 + t*16 + l15)*40 + quad*8]);
    }
    #pragma unroll
    for (int tm=0;tm<2;++tm)
      #pragma unroll
      for (int tn=0;tn<2;++tn)
        acc[tm][tn] = __builtin_amdgcn_mfma_f32_16x16x32_bf16(afr[tm], bfr[tn], acc[tm][tn], 0,0,0);
  }
  #pragma unroll
  for (int tm=0;tm<2;++tm)
    #pragma unroll
    for (int tn=0;tn<2;++tn)
      #pragma unroll
      for (int i=0;i<4;++i){
        int b = rb0 + wm*32 + tm*16 + quad*4 + i;
        int c = n0  + wn*32 + tn*16 + l15;
        float val = acc[tm][tn][i];
        if (FINAL){
          if (c < 256) val += bmu[c];
          else {
            val += bstd[c-256];
            val = fmaxf(val,0.f) + log1pf(__expf(-fabsf(val)));   // stable softplus
          }
          outF[((size_t)(c>>8)*BATCH + b)*256 + (c & 255)] = val;
        } else {
          out[((size_t)(c>>10)*BATCH + b)*HD + (c & 1023)] = f2bf(val);
        }
      }
}

// ---------------------------------------------------------------------------
extern "C" void kernel_launch(void* const* d_in, const int* in_sizes, int n_in,
                              void* d_out, int out_size, void* d_ws, size_t ws_size,
                              hipStream_t stream)
{
  const float* X    = (const float*)d_in[0];
  const int*   adj  = (const int*)  d_in[1];
  const float* Wihc = (const float*)d_in[2];
  const float* Whhc = (const float*)d_in[3];
  const float* bihc = (const float*)d_in[4];
  const float* bhhc = (const float*)d_in[5];
  const float* Wihl = (const float*)d_in[6];
  const float* Whhl = (const float*)d_in[7];
  const float* bihl = (const float*)d_in[8];
  const float* bhhl = (const float*)d_in[9];
  const float* Wihr = (const float*)d_in[10];
  const float* Whhr = (const float*)d_in[11];
  const float* bihr = (const float*)d_in[12];
  const float* bhhr = (const float*)d_in[13];
  const float* Wg   = (const float*)d_in[14];
  const float* bg   = (const float*)d_in[15];
  const float* Wm   = (const float*)d_in[16];
  const float* Wmu  = (const float*)d_in[17];
  const float* bmu  = (const float*)d_in[18];
  const float* Wstd = (const float*)d_in[19];
  const float* bstd = (const float*)d_in[20];
  float* out = (float*)d_out;

  // Workspace layout (bf16 elems), all segments 16B-aligned:
  bf16* P    = (bf16*)d_ws;                 // 24*BH
  bf16* Hin  = P    + 24*BH;                // BH
  bf16* Hva  = Hin  + BH;                   // BH
  bf16* Hvb  = Hva  + BH;                   // BH
  bf16* Wgmb = Hvb  + BH;                   // 4096*1024
  bf16* Wmsb = Wgmb + (size_t)4096*1024;    // 512*1024
  bf16* Whcb = Wmsb + (size_t)512*1024;     // 3072*1024
  bf16* Whlb = Whcb + (size_t)3072*1024;
  bf16* Whrb = Whlb + (size_t)3072*1024;
  bf16* Wicb = Whrb + (size_t)3072*1024;    // 3072*27 = 82944
  bf16* Wilb = Wicb + 82944;                // 3072*27
  bf16* Wirb = Wilb + 82944;                // 3072*23 = 70656
  bf16* Xb   = Wirb + 70656;                // 2048*7*27 = 387072

  // ---- One-shot weight/X conversion to bf16
  pack_wgm<<<4096, 256, 0, stream>>>(Wg, Wm, Wgmb);
  pack_wms<<<512,  256, 0, stream>>>(Wmu, Wstd, Wmsb);
  cvt4<<<3072, 256, 0, stream>>>(Whhc, Whcb, 786432);
  cvt4<<<3072, 256, 0, stream>>>(Whhl, Whlb, 786432);
  cvt4<<<3072, 256, 0, stream>>>(Whhr, Whrb, 786432);
  cvt4<<<81,   256, 0, stream>>>(Wihc, Wicb, 20736);
  cvt4<<<81,   256, 0, stream>>>(Wihl, Wilb, 20736);
  cvt4<<<69,   256, 0, stream>>>(Wihr, Wirb, 17664);
  cvt4<<<378,  256, 0, stream>>>(X,    Xb,   96768);

  for (int v=6; v>=1; --v){
    if (v < 6) combine_k<<<BATCH, 256, 0, stream>>>(P, adj, bg, Hin, v);
    // GRU-c: h = H_in (zeros for v==6: h_zero skips the K-loop and h read)
    gru_fused<<<dim3(32,16), 256, 0, stream>>>(Hin, Whcb, bhhc, Wicb, bihc, Xb, adj,
                                               v, 27, 0, (v==6)?1:0, Hva);
    // GRU-l: self-loop-masked x, h = Hv_c
    gru_fused<<<dim3(32,16), 256, 0, stream>>>(Hva, Whlb, bhhl, Wilb, bihl, Xb, adj,
                                               v, 27, 1, 0, Hvb);
    // P projections for node v (used by all later stages)
    gemm_bt<false><<<dim3(32,64), 256, 0, stream>>>(Hvb, Wgmb, P + (size_t)(v-1)*4*BH,
                                                    nullptr, nullptr, nullptr);
  }
  combine_k<<<BATCH, 256, 0, stream>>>(P, adj, bg, Hin, 0);
  gru_fused<<<dim3(32,16), 256, 0, stream>>>(Hin, Whrb, bhhr, Wirb, bihr, Xb, adj,
                                             0, 23, 0, 0, Hva);
  gemm_bt<true><<<dim3(32,8), 256, 0, stream>>>(Hva, Wmsb, nullptr, out, bmu, bstd);
}